// Round 6
// baseline (148.687 us; speedup 1.0000x reference)
//
#include <hip/hip_runtime.h>
#include <hip/hip_bf16.h>

// B=8, C=192, N=3136, K=9, COUT=384.
// out[b,o,n] = relu( bias[o] + max_k( u[b,i1,o] + v[b,i0,o] ) )
//   u = (W1-W2)·xs,  v = W2·xs   (per-node GEMMs; 9x less compute than per-edge)
// Dtype-adaptive (1-wave detect). Pipeline:
//   detect -> transpose_x (x -> x_T[b][n][200] bf16, padded rows) + prep_AT ([j][200] bf16)
//          -> gemm_mfma (pure granule staging, no LDS transpose) -> gather_max (channel-split)
// ws: flags @0 | A_Tb @1KB | x_T @512KB (10.0MB) | U @16MB | V (total ~55.3MB)

#define Bb   8
#define Cc   192
#define Nn   3136
#define Kk   9
#define CO   384
#define TWOC 384
#define JTOT 768
#define PADC 200   // padded row length (shorts): 400B rows -> +4 dword bank offset/row

typedef short  short8 __attribute__((ext_vector_type(8)));
typedef float  f32x4  __attribute__((ext_vector_type(4)));

__device__ __forceinline__ float bf2f(unsigned int u16) {
    union { unsigned int i; float f; } c;
    c.i = u16 << 16;
    return c.f;
}
__device__ __forceinline__ short f2bf(float f) {
    __hip_bfloat16 h = __float2bfloat16(f);
    short s; __builtin_memcpy(&s, &h, 2); return s;
}

// ---------------- detect input dtypes: one wave ----------------
__global__ __launch_bounds__(64) void detect(const unsigned short* __restrict__ xu,
                                             const int* __restrict__ ei,
                                             int* __restrict__ flags) {
    const int lane = threadIdx.x;
    unsigned int u = xu[2 * lane];
    int bige = (((u >> 7) & 0xFFu) >= 0x88u);       // impossible for N(0,1) bf16
    unsigned long long bf = __ballot(bige);
    int oddnz = (ei[2 * lane + 1] != 0);
    unsigned long long bo = __ballot(oddnz);
    if (lane == 0) {
        flags[0] = (bf != 0ull) ? 1 : 0;   // floats are fp32
        flags[1] = (bo == 0ull) ? 1 : 0;   // indices are int64
    }
}

// ---------------- prep: A_Tb[j][c] bf16 (PADC rows); j<384: W1-W2, j>=384: W2 ----------------
__global__ __launch_bounds__(256) void prep_AT(const void* __restrict__ W_,
                                               short* __restrict__ A_Tb,
                                               const int* __restrict__ flags) {
    const int fp32 = flags[0];
    int t = blockIdx.x * 256 + threadIdx.x;
    if (t >= JTOT * Cc) return;
    int j = t / Cc;
    int c = t - j * Cc;
    int row = (j < CO) ? j : (j - CO);
    float w1, w2;
    if (fp32) {
        const float* W = (const float*)W_;
        w1 = W[row * TWOC + c];  w2 = W[row * TWOC + Cc + c];
    } else {
        const unsigned short* W = (const unsigned short*)W_;
        w1 = bf2f(W[row * TWOC + c]);  w2 = bf2f(W[row * TWOC + Cc + c]);
    }
    A_Tb[(size_t)j * PADC + c] = f2bf((j < CO) ? (w1 - w2) : w2);
}

// ---------------- transpose_x: x[b][c][n] -> x_T[b][n][PADC] bf16 ----------------
// tile 32c x 64n, 256 threads
__global__ __launch_bounds__(256) void transpose_x(const void* __restrict__ x_,
                                                   short* __restrict__ xT,
                                                   const int* __restrict__ flags) {
    __shared__ float s[64][33];
    const int fp32 = flags[0];
    const int n0 = blockIdx.x * 64;
    const int c0 = blockIdx.y * 32;
    const int b  = blockIdx.z;
    const int t  = threadIdx.x;
    const int cl   = t >> 3;   // 0..31
    const int nseg = t & 7;    // 0..7

    if (fp32) {
        const float* p = (const float*)x_ + ((size_t)b * Cc + c0 + cl) * Nn + n0 + nseg * 8;
        float4 v0 = *(const float4*)p;
        float4 v1 = *(const float4*)(p + 4);
        int nb = nseg * 8;
        s[nb + 0][cl] = v0.x;  s[nb + 1][cl] = v0.y;
        s[nb + 2][cl] = v0.z;  s[nb + 3][cl] = v0.w;
        s[nb + 4][cl] = v1.x;  s[nb + 5][cl] = v1.y;
        s[nb + 6][cl] = v1.z;  s[nb + 7][cl] = v1.w;
    } else {
        const unsigned short* p = (const unsigned short*)x_ + ((size_t)b * Cc + c0 + cl) * Nn + n0 + nseg * 8;
        ushort4 u0 = *(const ushort4*)p;
        ushort4 u1 = *(const ushort4*)(p + 4);
        int nb = nseg * 8;
        s[nb + 0][cl] = bf2f(u0.x);  s[nb + 1][cl] = bf2f(u0.y);
        s[nb + 2][cl] = bf2f(u0.z);  s[nb + 3][cl] = bf2f(u0.w);
        s[nb + 4][cl] = bf2f(u1.x);  s[nb + 5][cl] = bf2f(u1.y);
        s[nb + 6][cl] = bf2f(u1.z);  s[nb + 7][cl] = bf2f(u1.w);
    }
    __syncthreads();

    const int nl = t >> 2;     // 0..63
    const int cs = t & 3;      // 0..3
    short8 o;
#pragma unroll
    for (int i = 0; i < 8; ++i) o[i] = f2bf(s[nl][cs * 8 + i]);
    *(short8*)(xT + ((size_t)b * Nn + n0 + nl) * PADC + c0 + cs * 8) = o;
}

// ---------------- MFMA GEMM: T[b][n][j] = sum_c x_T[b][n][c] * A_Tb[j][c] ----------------
// tile 64(n) x 256(j), K-step 32; 4 waves: wave w covers j-range [w*64, w*64+64)
#define MT 64
#define NT 256
#define KT 32
#define LPAD 40   // LDS row stride (shorts); granule staging is bank-balanced (floor-rate)

__global__ __launch_bounds__(256) void gemm_mfma(const short* __restrict__ xT,
                                                 const short* __restrict__ A_Tb,
                                                 short* __restrict__ U,
                                                 short* __restrict__ V) {
    __shared__ short Asl[MT * LPAD];   // [n][c]  5,120 B
    __shared__ short Bsl[NT * LPAD];   // [j][c] 20,480 B

    const int n0 = blockIdx.x * MT;
    const int j0 = blockIdx.y * NT;
    const int b  = blockIdx.z;
    const int tid  = threadIdx.x;
    const int w    = tid >> 6;
    const int lane = tid & 63;
    const int col  = lane & 15;
    const int quad = lane >> 4;

    f32x4 acc[4][4];
#pragma unroll
    for (int i = 0; i < 4; ++i)
#pragma unroll
        for (int jf = 0; jf < 4; ++jf) acc[i][jf] = (f32x4)(0.0f);

    const int ar = tid >> 2;   // row 0..63
    const int ag = tid & 3;    // granule 0..3

    for (int c0 = 0; c0 < Cc; c0 += KT) {
        // stage A: straight 16B granule copies (no transpose)
        *(short8*)(Asl + ar * LPAD + ag * 8) =
            *(const short8*)(xT + ((size_t)b * Nn + n0 + ar) * PADC + c0 + ag * 8);
        // stage B: 4 granules per thread
#pragma unroll
        for (int h = 0; h < 4; ++h) {
            int row = h * 64 + ar;
            *(short8*)(Bsl + row * LPAD + ag * 8) =
                *(const short8*)(A_Tb + (size_t)(j0 + row) * PADC + c0 + ag * 8);
        }
        __syncthreads();

        // A[m=lane&15][k=quad*8+i], B[k=quad*8+i][n=lane&15], D[row=quad*4+r][col=lane&15]
        short8 bf[4];
#pragma unroll
        for (int jf = 0; jf < 4; ++jf)
            bf[jf] = *(const short8*)(&Bsl[(w * 64 + jf * 16 + col) * LPAD + quad * 8]);
#pragma unroll
        for (int fm = 0; fm < 4; ++fm) {
            short8 a = *(const short8*)(&Asl[(fm * 16 + col) * LPAD + quad * 8]);
#pragma unroll
            for (int jf = 0; jf < 4; ++jf)
                acc[fm][jf] = __builtin_amdgcn_mfma_f32_16x16x32_bf16(a, bf[jf], acc[fm][jf], 0, 0, 0);
        }
        __syncthreads();
    }

    // epilogue: U/V bf16 [b][n][384]
    const int jbase = j0 + w * 64;
#pragma unroll
    for (int fn = 0; fn < 4; ++fn) {
        int j = jbase + fn * 16 + col;
        short* dst; int jj;
        if (j < CO) { dst = U; jj = j; } else { dst = V; jj = j - CO; }
#pragma unroll
        for (int fm = 0; fm < 4; ++fm) {
#pragma unroll
            for (int r = 0; r < 4; ++r) {
                int n = n0 + fm * 16 + quad * 4 + r;
                dst[((size_t)(b * Nn + n)) * CO + jj] = f2bf(acc[fm][fn][r]);
            }
        }
    }
}

// ---------------- gather + max + bias + relu, channel-split for L2 residency ----------------
// bid = b + 8*(tile + 98*half): one (b, half) per XCD for long stretches;
// per-XCD working set = U-half + V-half of one batch = 2.4 MB < 4 MB L2.
__global__ __launch_bounds__(384) void gather_max(const int* __restrict__ ei,
                                                  const short* __restrict__ U,
                                                  const short* __restrict__ V,
                                                  const void* __restrict__ bias_,
                                                  void* __restrict__ out_,
                                                  const int* __restrict__ flags) {
    __shared__ float sm[32][193];   // [node][local channel], pad: column reads conflict-free
    __shared__ int si0[32][Kk];
    __shared__ int si1[32][Kk];

    const int fp32 = flags[0];
    const int is64 = flags[1];
    const int bid  = blockIdx.x;
    const int b    = bid & 7;
    const int rest = bid >> 3;        // 0..195
    const int half = rest / 98;       // 0,1
    const int n0   = (rest % 98) * 32;
    const int tid  = threadIdx.x;

    for (int s = tid; s < 32 * 2 * Kk; s += 384) {
        int ln = s / (2 * Kk);
        int slot = s - ln * (2 * Kk);
        int n = n0 + ln;
        size_t pos; int* dstp;
        if (slot < Kk) { pos = ((size_t)b * Nn + n) * Kk + slot;               dstp = &si0[ln][slot]; }
        else           { pos = ((size_t)(Bb + b) * Nn + n) * Kk + (slot - Kk); dstp = &si1[ln][slot - Kk]; }
        int v = is64 ? ei[2 * pos] : ei[pos];
        *dstp = (v < 0) ? 0 : (v >= Nn ? Nn - 1 : v);
    }
    __syncthreads();

    const int p   = tid % 96;         // channel pair within half
    const int seg = tid / 96;         // 0..3 -> nodes seg*8 .. seg*8+7
    const int och = half * 192 + 2 * p;
    const unsigned short* Ub = (const unsigned short*)U + (size_t)b * Nn * CO;
    const unsigned short* Vb = (const unsigned short*)V + (size_t)b * Nn * CO;

    float b0, b1;
    if (fp32) {
        b0 = ((const float*)bias_)[och];
        b1 = ((const float*)bias_)[och + 1];
    } else {
        b0 = bf2f(((const unsigned short*)bias_)[och]);
        b1 = bf2f(((const unsigned short*)bias_)[och + 1]);
    }

    for (int ln = seg * 8; ln < seg * 8 + 8; ++ln) {
        float m0 = -INFINITY, m1 = -INFINITY;
#pragma unroll
        for (int k = 0; k < Kk; ++k) {
            unsigned int uu = *(const unsigned int*)(Ub + (size_t)si1[ln][k] * CO + och);
            unsigned int vv = *(const unsigned int*)(Vb + (size_t)si0[ln][k] * CO + och);
            m0 = fmaxf(m0, bf2f(uu & 0xffffu) + bf2f(vv & 0xffffu));
            m1 = fmaxf(m1, bf2f(uu >> 16) + bf2f(vv >> 16));
        }
        sm[ln][2 * p]     = fmaxf(m0 + b0, 0.0f);
        sm[ln][2 * p + 1] = fmaxf(m1 + b1, 0.0f);
    }
    __syncthreads();

    // transposed write: 12 groups x 16 rows; lane l writes n0+l (coalesced 32-wide)
    const int g = tid >> 5, l = tid & 31;
    if (fp32) {
        float* op = (float*)out_;
#pragma unroll
        for (int rr = 0; rr < 16; ++rr) {
            int ol = g * 16 + rr;
            int o  = half * 192 + ol;
            op[((size_t)b * CO + o) * Nn + n0 + l] = sm[l][ol];
        }
    } else {
        __hip_bfloat16* op = (__hip_bfloat16*)out_;
#pragma unroll
        for (int rr = 0; rr < 16; ++rr) {
            int ol = g * 16 + rr;
            int o  = half * 192 + ol;
            op[((size_t)b * CO + o) * Nn + n0 + l] = __float2bfloat16(sm[l][ol]);
        }
    }
}

extern "C" void kernel_launch(void* const* d_in, const int* in_sizes, int n_in,
                              void* d_out, int out_size, void* d_ws, size_t ws_size,
                              hipStream_t stream) {
    const void* x  = d_in[0];
    const int*  ei = (const int*)d_in[1];
    const void* W  = d_in[2];
    const void* bs = d_in[3];

    char* ws = (char*)d_ws;
    int*   flags = (int*)ws;                               // 64 B
    short* A_Tb  = (short*)(ws + 1024);                    // 768*200*2 = 307,200 B
    short* xT    = (short*)(ws + (512u << 10));            // 8*3136*200*2 = 10,035,200 B
    short* U     = (short*)(ws + (16u << 20));             // 19,267,584 B
    short* V     = U + (size_t)Bb * Nn * CO;               // 19,267,584 B  (ends ~55.3 MB)

    detect<<<1, 64, 0, stream>>>((const unsigned short*)x, ei, flags);

    prep_AT<<<(JTOT * Cc + 255) / 256, 256, 0, stream>>>(W, A_Tb, flags);

    dim3 gt(Nn / 64, Cc / 32, Bb);     // (49, 6, 8)
    transpose_x<<<gt, 256, 0, stream>>>(x, xT, flags);

    dim3 g1(Nn / MT, JTOT / NT, Bb);   // (49, 3, 8)
    gemm_mfma<<<g1, 256, 0, stream>>>(xT, A_Tb, U, V);

    gather_max<<<Bb * 2 * (Nn / 32), 384, 0, stream>>>(ei, U, V, bs, d_out, flags);
}

// Round 7
// 146.248 us; speedup vs baseline: 1.0167x; 1.0167x over previous
//
#include <hip/hip_runtime.h>
#include <hip/hip_bf16.h>

// B=8, C=192, N=3136, K=9, COUT=384.
// out[b,o,n] = relu( bias[o] + max_k( u[b,i1,o] + v[b,i0,o] ) )
//   u = (W1-W2)·xs,  v = W2·xs   (per-node GEMMs; 9x less compute than per-edge)
// 3-kernel pipeline (launch overhead matters):
//   prep_fused: inline-detect dtypes + x->x_T[b][n][200] bf16 + W->A_Tb[j][200] bf16
//   gemm_mfma : T[b][n][768] = x_T · A_Tb^T   (bank-conflict-free granule staging)
//   gather_max: channel-split gather + max + bias + relu, coalesced transposed writes
// ws: flags @0 | A_Tb @1KB (307KB) | x_T @512KB (10.0MB) | T @11MB (38.5MB) ~= 49.5MB

#define Bb   8
#define Cc   192
#define Nn   3136
#define Kk   9
#define CO   384
#define TWOC 384
#define JTOT 768
#define PADC 200   // padded row length (shorts): 400B rows

typedef short  short8 __attribute__((ext_vector_type(8)));
typedef float  f32x4  __attribute__((ext_vector_type(4)));

__device__ __forceinline__ float bf2f(unsigned int u16) {
    union { unsigned int i; float f; } c;
    c.i = u16 << 16;
    return c.f;
}
__device__ __forceinline__ short f2bf(float f) {
    __hip_bfloat16 h = __float2bfloat16(f);
    short s; __builtin_memcpy(&s, &h, 2); return s;
}

// ---------------- K1: fused detect + transpose_x + prep_AT ----------------
// blocks 0..2351: transpose tiles (32c x 64n); blocks 2352..2927: prep_AT.
// Every block inline-detects fp32 from x's first 256B (L2-broadcast, ~free);
// block 0 publishes both flags to ws for gather_max.
__global__ __launch_bounds__(256) void prep_fused(const void* __restrict__ x_,
                                                  const void* __restrict__ W_,
                                                  const int* __restrict__ ei,
                                                  short* __restrict__ xT,
                                                  short* __restrict__ A_Tb,
                                                  int* __restrict__ flags) {
    __shared__ float s[64][33];
    __shared__ int sflag;
    const int tid = threadIdx.x;
    const int bid = blockIdx.x;

    if (tid < 64) {
        unsigned int u = ((const unsigned short*)x_)[2 * tid];
        int bige = (((u >> 7) & 0xFFu) >= 0x88u);   // impossible for N(0,1) bf16
        unsigned long long bf = __ballot(bige);
        int f32 = (bf != 0ull) ? 1 : 0;
        if (tid == 0) sflag = f32;
        if (bid == 0) {
            int oddnz = (ei[2 * tid + 1] != 0);
            unsigned long long bo = __ballot(oddnz);
            if (tid == 0) {
                flags[0] = f32;                      // floats are fp32
                flags[1] = (bo == 0ull) ? 1 : 0;     // indices are int64
            }
        }
    }
    __syncthreads();
    const int fp32 = sflag;

    if (bid < 2352) {
        // ---- transpose tile: bid -> (b, ct, nt) ----
        int b   = bid / 294;              // 294 = 6*49
        int rem = bid - b * 294;
        int ct  = rem / 49;
        int nt  = rem - ct * 49;
        const int n0 = nt * 64;
        const int c0 = ct * 32;
        const int cl   = tid >> 3;   // 0..31
        const int nseg = tid & 7;    // 0..7

        if (fp32) {
            const float* p = (const float*)x_ + ((size_t)b * Cc + c0 + cl) * Nn + n0 + nseg * 8;
            float4 v0 = *(const float4*)p;
            float4 v1 = *(const float4*)(p + 4);
            int nb = nseg * 8;
            s[nb + 0][cl] = v0.x;  s[nb + 1][cl] = v0.y;
            s[nb + 2][cl] = v0.z;  s[nb + 3][cl] = v0.w;
            s[nb + 4][cl] = v1.x;  s[nb + 5][cl] = v1.y;
            s[nb + 6][cl] = v1.z;  s[nb + 7][cl] = v1.w;
        } else {
            const unsigned short* p = (const unsigned short*)x_ + ((size_t)b * Cc + c0 + cl) * Nn + n0 + nseg * 8;
            ushort4 u0 = *(const ushort4*)p;
            ushort4 u1 = *(const ushort4*)(p + 4);
            int nb = nseg * 8;
            s[nb + 0][cl] = bf2f(u0.x);  s[nb + 1][cl] = bf2f(u0.y);
            s[nb + 2][cl] = bf2f(u0.z);  s[nb + 3][cl] = bf2f(u0.w);
            s[nb + 4][cl] = bf2f(u1.x);  s[nb + 5][cl] = bf2f(u1.y);
            s[nb + 6][cl] = bf2f(u1.z);  s[nb + 7][cl] = bf2f(u1.w);
        }
        __syncthreads();

        const int nl = tid >> 2;     // 0..63
        const int cs = tid & 3;      // 0..3
        short8 o;
#pragma unroll
        for (int i = 0; i < 8; ++i) o[i] = f2bf(s[nl][cs * 8 + i]);
        *(short8*)(xT + ((size_t)b * Nn + n0 + nl) * PADC + c0 + cs * 8) = o;
    } else {
        // ---- prep_AT: A_Tb[j][c]; j<384: W1-W2, j>=384: W2 ----
        int t = (bid - 2352) * 256 + tid;        // 0..147455 exactly
        int j = t / Cc;
        int c = t - j * Cc;
        int row = (j < CO) ? j : (j - CO);
        float w1, w2;
        if (fp32) {
            const float* W = (const float*)W_;
            w1 = W[row * TWOC + c];  w2 = W[row * TWOC + Cc + c];
        } else {
            const unsigned short* W = (const unsigned short*)W_;
            w1 = bf2f(W[row * TWOC + c]);  w2 = bf2f(W[row * TWOC + Cc + c]);
        }
        A_Tb[(size_t)j * PADC + c] = f2bf((j < CO) ? (w1 - w2) : w2);
    }
}

// ---------------- K2: MFMA GEMM: T[b][n][j] = sum_c x_T[b][n][c] * A_Tb[j][c] ----------------
// tile 64(n) x 256(j), K-step 32; 4 waves: wave w covers j-range [w*64, w*64+64)
#define MT 64
#define NT 256
#define KT 32
#define LPAD 40   // LDS row stride (shorts); granule staging/reads are floor-rate (8/bank)

__global__ __launch_bounds__(256) void gemm_mfma(const short* __restrict__ xT,
                                                 const short* __restrict__ A_Tb,
                                                 short* __restrict__ T) {
    __shared__ short Asl[MT * LPAD];   // [n][c]  5,120 B
    __shared__ short Bsl[NT * LPAD];   // [j][c] 20,480 B

    const int n0 = blockIdx.x * MT;
    const int j0 = blockIdx.y * NT;
    const int b  = blockIdx.z;
    const int tid  = threadIdx.x;
    const int w    = tid >> 6;
    const int lane = tid & 63;
    const int col  = lane & 15;
    const int quad = lane >> 4;

    f32x4 acc[4][4];
#pragma unroll
    for (int i = 0; i < 4; ++i)
#pragma unroll
        for (int jf = 0; jf < 4; ++jf) acc[i][jf] = (f32x4)(0.0f);

    const int ar = tid >> 2;   // row 0..63
    const int ag = tid & 3;    // granule 0..3

    for (int c0 = 0; c0 < Cc; c0 += KT) {
        *(short8*)(Asl + ar * LPAD + ag * 8) =
            *(const short8*)(xT + ((size_t)b * Nn + n0 + ar) * PADC + c0 + ag * 8);
#pragma unroll
        for (int h = 0; h < 4; ++h) {
            int row = h * 64 + ar;
            *(short8*)(Bsl + row * LPAD + ag * 8) =
                *(const short8*)(A_Tb + (size_t)(j0 + row) * PADC + c0 + ag * 8);
        }
        __syncthreads();

        // A[m=lane&15][k=quad*8+i], B[k=quad*8+i][n=lane&15], D[row=quad*4+r][col=lane&15]
        short8 bf[4];
#pragma unroll
        for (int jf = 0; jf < 4; ++jf)
            bf[jf] = *(const short8*)(&Bsl[(w * 64 + jf * 16 + col) * LPAD + quad * 8]);
#pragma unroll
        for (int fm = 0; fm < 4; ++fm) {
            short8 a = *(const short8*)(&Asl[(fm * 16 + col) * LPAD + quad * 8]);
#pragma unroll
            for (int jf = 0; jf < 4; ++jf)
                acc[fm][jf] = __builtin_amdgcn_mfma_f32_16x16x32_bf16(a, bf[jf], acc[fm][jf], 0, 0, 0);
        }
        __syncthreads();
    }

    // epilogue: T[b][n][768] — contiguous j per n-row
    const int jbase = j0 + w * 64;
#pragma unroll
    for (int fn = 0; fn < 4; ++fn) {
        int j = jbase + fn * 16 + col;
#pragma unroll
        for (int fm = 0; fm < 4; ++fm) {
#pragma unroll
            for (int r = 0; r < 4; ++r) {
                int n = n0 + fm * 16 + quad * 4 + r;
                T[((size_t)(b * Nn + n)) * JTOT + j] = f2bf(acc[fm][fn][r]);
            }
        }
    }
}

// ---------------- K3: gather + max + bias + relu (channel-split for L2 residency) ----------------
// bid = b + 8*(tile + 98*half); per-XCD working set ~2.4MB < 4MB L2.
__global__ __launch_bounds__(384) void gather_max(const int* __restrict__ ei,
                                                  const short* __restrict__ T,
                                                  const void* __restrict__ bias_,
                                                  void* __restrict__ out_,
                                                  const int* __restrict__ flags) {
    __shared__ float sm[32][193];
    __shared__ int si0[32][Kk];
    __shared__ int si1[32][Kk];

    const int fp32 = flags[0];
    const int is64 = flags[1];
    const int bid  = blockIdx.x;
    const int b    = bid & 7;
    const int rest = bid >> 3;        // 0..195
    const int half = rest / 98;       // 0,1
    const int n0   = (rest % 98) * 32;
    const int tid  = threadIdx.x;

    for (int s = tid; s < 32 * 2 * Kk; s += 384) {
        int ln = s / (2 * Kk);
        int slot = s - ln * (2 * Kk);
        int n = n0 + ln;
        size_t pos; int* dstp;
        if (slot < Kk) { pos = ((size_t)b * Nn + n) * Kk + slot;               dstp = &si0[ln][slot]; }
        else           { pos = ((size_t)(Bb + b) * Nn + n) * Kk + (slot - Kk); dstp = &si1[ln][slot - Kk]; }
        int v = is64 ? ei[2 * pos] : ei[pos];
        *dstp = (v < 0) ? 0 : (v >= Nn ? Nn - 1 : v);
    }
    __syncthreads();

    const int p   = tid % 96;         // channel pair within half
    const int seg = tid / 96;         // 0..3 -> nodes seg*8 .. seg*8+7
    const int och = half * 192 + 2 * p;
    const unsigned short* Tb = (const unsigned short*)T + (size_t)b * Nn * JTOT;

    float b0, b1;
    if (fp32) {
        b0 = ((const float*)bias_)[och];
        b1 = ((const float*)bias_)[och + 1];
    } else {
        b0 = bf2f(((const unsigned short*)bias_)[och]);
        b1 = bf2f(((const unsigned short*)bias_)[och + 1]);
    }

    for (int ln = seg * 8; ln < seg * 8 + 8; ++ln) {
        float m0 = -INFINITY, m1 = -INFINITY;
#pragma unroll
        for (int k = 0; k < Kk; ++k) {
            unsigned int uu = *(const unsigned int*)(Tb + (size_t)si1[ln][k] * JTOT + och);
            unsigned int vv = *(const unsigned int*)(Tb + (size_t)si0[ln][k] * JTOT + CO + och);
            m0 = fmaxf(m0, bf2f(uu & 0xffffu) + bf2f(vv & 0xffffu));
            m1 = fmaxf(m1, bf2f(uu >> 16) + bf2f(vv >> 16));
        }
        sm[ln][2 * p]     = fmaxf(m0 + b0, 0.0f);
        sm[ln][2 * p + 1] = fmaxf(m1 + b1, 0.0f);
    }
    __syncthreads();

    // transposed write: 12 groups x 16 rows; lane l writes n0+l (coalesced 32-wide)
    const int g = tid >> 5, l = tid & 31;
    if (fp32) {
        float* op = (float*)out_;
#pragma unroll
        for (int rr = 0; rr < 16; ++rr) {
            int ol = g * 16 + rr;
            int o  = half * 192 + ol;
            op[((size_t)b * CO + o) * Nn + n0 + l] = sm[l][ol];
        }
    } else {
        __hip_bfloat16* op = (__hip_bfloat16*)out_;
#pragma unroll
        for (int rr = 0; rr < 16; ++rr) {
            int ol = g * 16 + rr;
            int o  = half * 192 + ol;
            op[((size_t)b * CO + o) * Nn + n0 + l] = __float2bfloat16(sm[l][ol]);
        }
    }
}

extern "C" void kernel_launch(void* const* d_in, const int* in_sizes, int n_in,
                              void* d_out, int out_size, void* d_ws, size_t ws_size,
                              hipStream_t stream) {
    const void* x  = d_in[0];
    const int*  ei = (const int*)d_in[1];
    const void* W  = d_in[2];
    const void* bs = d_in[3];

    char* ws = (char*)d_ws;
    int*   flags = (int*)ws;                               // 64 B
    short* A_Tb  = (short*)(ws + 1024);                    // 768*200*2 = 307,200 B
    short* xT    = (short*)(ws + (512u << 10));            // 8*3136*200*2 = 10,035,200 B
    short* T     = (short*)(ws + (11u << 20));             // 8*3136*768*2 = 38,535,168 B

    prep_fused<<<2352 + 576, 256, 0, stream>>>(x, W, ei, xT, A_Tb, flags);

    dim3 g1(Nn / MT, JTOT / NT, Bb);   // (49, 3, 8)
    gemm_mfma<<<g1, 256, 0, stream>>>(xT, A_Tb, T);

    gather_max<<<Bb * 2 * (Nn / 32), 384, 0, stream>>>(ei, T, bs, d_out, flags);
}